// Round 1
// baseline (1546.128 us; speedup 1.0000x reference)
//
#include <hip/hip_runtime.h>

#define NN 20000     // nodes
#define NE 320000    // edges
#define NG 64        // graphs
#define DIN 128
#define DH 64
#define NH 8
#define HD 512       // NH*DH
#define NC 32

// ---------------- input linear: [NN,128] @ [128,64] + b ----------------
__global__ __launch_bounds__(256) void k_gemm_in(const float* __restrict__ A,
    const float* __restrict__ W, const float* __restrict__ b, float* __restrict__ out) {
  __shared__ float As[16][DIN];
  int c = threadIdx.x & 63;
  int rg = threadIdx.x >> 6;           // 0..3
  int row0 = blockIdx.x * 16;
  for (int i = threadIdx.x; i < 16 * DIN; i += 256) {
    int r = i >> 7, k = i & 127;
    int gr = row0 + r;
    As[r][k] = (gr < NN) ? A[gr * DIN + k] : 0.f;
  }
  __syncthreads();
  float acc[4] = {0.f, 0.f, 0.f, 0.f};
  for (int k = 0; k < DIN; ++k) {
    float w = W[k * DH + c];
#pragma unroll
    for (int i = 0; i < 4; ++i) acc[i] += As[rg * 4 + i][k] * w;
  }
  float bias = b[c];
#pragma unroll
  for (int i = 0; i < 4; ++i) {
    int gr = row0 + rg * 4 + i;
    if (gr < NN) out[gr * DH + c] = acc[i] + bias;
  }
}

// ---------------- hidden linear: [NN,64] @ [64,512] + b ----------------
__global__ __launch_bounds__(512) void k_gemm_h512(const float* __restrict__ A,
    const float* __restrict__ W, const float* __restrict__ b, float* __restrict__ out) {
  __shared__ float As[16][DH];
  int c = threadIdx.x;                 // 0..511
  int row0 = blockIdx.x * 16;
  for (int i = threadIdx.x; i < 16 * DH; i += 512) {
    int r = i >> 6, k = i & 63;
    int gr = row0 + r;
    As[r][k] = (gr < NN) ? A[gr * DH + k] : 0.f;
  }
  __syncthreads();
  float acc[16];
#pragma unroll
  for (int i = 0; i < 16; ++i) acc[i] = 0.f;
  for (int k = 0; k < DH; ++k) {
    float w = W[k * HD + c];
#pragma unroll
    for (int i = 0; i < 16; ++i) acc[i] += As[i][k] * w;
  }
  float bias = b[c];
#pragma unroll
  for (int i = 0; i < 16; ++i) {
    int gr = row0 + i;
    if (gr < NN) out[gr * HD + c] = acc[i] + bias;
  }
}

// ---------------- CSR build ----------------
__global__ void k_hist(const int* __restrict__ dst, int* __restrict__ counts) {
  int e = blockIdx.x * blockDim.x + threadIdx.x;
  if (e < NE) atomicAdd(&counts[dst[e]], 1);
}

__global__ __launch_bounds__(1024) void k_scan(const int* __restrict__ counts,
    int* __restrict__ row_start, int* __restrict__ cursor) {
  __shared__ int partial[1024];
  const int CH = (NN + 1023) / 1024;   // 20
  int t = threadIdx.x;
  int base = t * CH;
  int s = 0;
  for (int i = 0; i < CH; ++i) {
    int idx = base + i;
    if (idx < NN) s += counts[idx];
  }
  partial[t] = s;
  __syncthreads();
  for (int off = 1; off < 1024; off <<= 1) {
    int v = (t >= off) ? partial[t - off] : 0;
    __syncthreads();
    partial[t] += v;
    __syncthreads();
  }
  int prefix = (t > 0) ? partial[t - 1] : 0;
  for (int i = 0; i < CH; ++i) {
    int idx = base + i;
    if (idx < NN) {
      row_start[idx] = prefix;
      cursor[idx] = prefix;
      prefix += counts[idx];
    }
  }
  if (t == 1023) row_start[NN] = partial[1023];
}

__global__ void k_scatter(const int* __restrict__ dst, int* __restrict__ cursor,
                          int* __restrict__ eid) {
  int e = blockIdx.x * blockDim.x + threadIdx.x;
  if (e < NE) {
    int p = atomicAdd(&cursor[dst[e]], 1);
    eid[p] = e;
  }
}

// ---------------- edge scores: attn . leaky_relu(fs[src]+fd[dst]) ----------------
// one block per edge, 8 waves = 8 heads, lane = feature dim
__global__ __launch_bounds__(512) void k_edge_scores(const float* __restrict__ fs,
    const float* __restrict__ fd, const int* __restrict__ src, const int* __restrict__ dst,
    const float* __restrict__ attn, float* __restrict__ scores) {
  int e = blockIdx.x;
  int h = threadIdx.x >> 6, lane = threadIdx.x & 63;
  int s = src[e], d = dst[e];
  float x = fs[s * HD + h * DH + lane] + fd[d * HD + h * DH + lane];
  x = (x > 0.f) ? x : 0.2f * x;
  float p = attn[h * DH + lane] * x;
#pragma unroll
  for (int off = 32; off > 0; off >>= 1) p += __shfl_xor(p, off, 64);
  if (lane == 0) scores[e * NH + h] = p;
}

// ---------------- per-node online softmax + aggregation + head-mean ----------------
// one block per node, 8 waves = 8 heads, lane = feature dim
__global__ __launch_bounds__(512) void k_aggregate(const float* __restrict__ fs,
    const float* __restrict__ scores, const int* __restrict__ src,
    const int* __restrict__ row_start, const int* __restrict__ eid,
    const float* __restrict__ bias, float* __restrict__ hout, int do_relu) {
  int v = blockIdx.x;
  int h = threadIdx.x >> 6, lane = threadIdx.x & 63;
  int beg = row_start[v], end = row_start[v + 1];
  float m = -3.4e38f, sum = 0.f, acc = 0.f;
  for (int j = beg; j < end; ++j) {
    int e = eid[j];
    float sc = scores[e * NH + h];
    int sn = src[e];
    float fv = fs[sn * HD + h * DH + lane];
    float mn = fmaxf(m, sc);
    float scale = __expf(m - mn);
    float w = __expf(sc - mn);
    acc = acc * scale + w * fv;
    sum = sum * scale + w;
    m = mn;
  }
  __shared__ float sh[NH * DH];
  sh[threadIdx.x] = acc / fmaxf(sum, 1e-9f) + bias[h * DH + lane];
  __syncthreads();
  if (threadIdx.x < DH) {
    float s = 0.f;
#pragma unroll
    for (int hh = 0; hh < NH; ++hh) s += sh[hh * DH + threadIdx.x];
    s *= (1.f / NH);
    if (do_relu) s = fmaxf(s, 0.f);
    hout[v * DH + threadIdx.x] = s;
  }
}

// ---------------- graph mean readout (accumulate) ----------------
__global__ __launch_bounds__(256) void k_readout(const float* __restrict__ h,
    const int* __restrict__ gid, float* __restrict__ gsum, int* __restrict__ gcount) {
  int wid = (blockIdx.x * 256 + threadIdx.x) >> 6;
  int lane = threadIdx.x & 63;
  if (wid >= NN) return;
  int g = gid[wid];
  atomicAdd(&gsum[g * DH + lane], h[wid * DH + lane]);
  if (lane == 0) atomicAdd(&gcount[g], 1);
}

// ---------------- classification head, one block per graph ----------------
__global__ __launch_bounds__(64) void k_head(const float* __restrict__ gsum,
    const int* __restrict__ gcount, const float* __restrict__ Wh1,
    const float* __restrict__ bh1, const float* __restrict__ Wh2,
    const float* __restrict__ bh2, float* __restrict__ out) {
  int g = blockIdx.x;
  int t = threadIdx.x;  // 64
  __shared__ float hg[DH];
  __shared__ float hid[DH];
  __shared__ float logits[NC];
  float cnt = fmaxf((float)gcount[g], 1.0f);
  hg[t] = gsum[g * DH + t] / cnt;
  __syncthreads();
  float a = 0.f;
  for (int k = 0; k < DH; ++k) a += hg[k] * Wh1[k * DH + t];
  hid[t] = fmaxf(a + bh1[t], 0.f);
  __syncthreads();
  if (t < NC) {
    float l = 0.f;
    for (int k = 0; k < DH; ++k) l += hid[k] * Wh2[k * NC + t];
    logits[t] = l + bh2[t];
  }
  __syncthreads();
  if (t == 0) {
    float mx = logits[0];
    for (int i = 1; i < NC; ++i) mx = fmaxf(mx, logits[i]);
    float s = 0.f;
    for (int i = 0; i < NC; ++i) {
      float w = __expf(logits[i] - mx);
      logits[i] = w;
      s += w;
    }
    float inv = 1.f / s;
    for (int i = 0; i < NC; ++i) out[g * NC + i] = logits[i] * inv;
  }
}

extern "C" void kernel_launch(void* const* d_in, const int* in_sizes, int n_in,
                              void* d_out, int out_size, void* d_ws, size_t ws_size,
                              hipStream_t stream) {
  const float* g_feats = (const float*)d_in[0];
  const int*   src     = (const int*)d_in[1];
  const int*   dst     = (const int*)d_in[2];
  const int*   gid     = (const int*)d_in[3];
  const float* W_in    = (const float*)d_in[4];
  const float* b_in    = (const float*)d_in[5];
  const float* Wsrc1   = (const float*)d_in[6];
  const float* bsrc1   = (const float*)d_in[7];
  const float* Wdst1   = (const float*)d_in[8];
  const float* bdst1   = (const float*)d_in[9];
  const float* attn1   = (const float*)d_in[10];
  const float* bias1   = (const float*)d_in[11];
  const float* Wsrc2   = (const float*)d_in[12];
  const float* bsrc2   = (const float*)d_in[13];
  const float* Wdst2   = (const float*)d_in[14];
  const float* bdst2   = (const float*)d_in[15];
  const float* attn2   = (const float*)d_in[16];
  const float* bias2   = (const float*)d_in[17];
  const float* Wh1     = (const float*)d_in[18];
  const float* bh1     = (const float*)d_in[19];
  const float* Wh2     = (const float*)d_in[20];
  const float* bh2     = (const float*)d_in[21];

  char* ws = (char*)d_ws;
  size_t off = 0;
  auto A = [&](size_t bytes) -> char* {
    char* p = ws + off;
    off = (off + bytes + 255) & ~(size_t)255;
    return p;
  };
  float* h0     = (float*)A((size_t)NN * DH * 4);
  float* h1     = (float*)A((size_t)NN * DH * 4);
  float* h2     = (float*)A((size_t)NN * DH * 4);
  float* fs     = (float*)A((size_t)NN * HD * 4);
  float* fd     = (float*)A((size_t)NN * HD * 4);
  float* scores = (float*)A((size_t)NE * NH * 4);
  int*   row_start = (int*)A((size_t)(NN + 1) * 4);
  int*   cursor    = (int*)A((size_t)NN * 4);
  int*   eid       = (int*)A((size_t)NE * 4);
  // zero region: counts, gcount, gsum contiguous
  char*  zero_base = A((size_t)NN * 4);           // counts
  int*   counts    = (int*)zero_base;
  int*   gcount    = (int*)A((size_t)NG * 4);
  float* gsum      = (float*)A((size_t)NG * DH * 4);
  size_t zero_span = (size_t)((char*)gsum + (size_t)NG * DH * 4 - zero_base);

  hipMemsetAsync(zero_base, 0, zero_span, stream);

  k_gemm_in<<<(NN + 15) / 16, 256, 0, stream>>>(g_feats, W_in, b_in, h0);
  k_hist<<<(NE + 255) / 256, 256, 0, stream>>>(dst, counts);
  k_scan<<<1, 1024, 0, stream>>>(counts, row_start, cursor);
  k_scatter<<<(NE + 255) / 256, 256, 0, stream>>>(dst, cursor, eid);

  // layer 1
  k_gemm_h512<<<(NN + 15) / 16, 512, 0, stream>>>(h0, Wsrc1, bsrc1, fs);
  k_gemm_h512<<<(NN + 15) / 16, 512, 0, stream>>>(h0, Wdst1, bdst1, fd);
  k_edge_scores<<<NE, 512, 0, stream>>>(fs, fd, src, dst, attn1, scores);
  k_aggregate<<<NN, 512, 0, stream>>>(fs, scores, src, row_start, eid, bias1, h1, 1);

  // layer 2
  k_gemm_h512<<<(NN + 15) / 16, 512, 0, stream>>>(h1, Wsrc2, bsrc2, fs);
  k_gemm_h512<<<(NN + 15) / 16, 512, 0, stream>>>(h1, Wdst2, bdst2, fd);
  k_edge_scores<<<NE, 512, 0, stream>>>(fs, fd, src, dst, attn2, scores);
  k_aggregate<<<NN, 512, 0, stream>>>(fs, scores, src, row_start, eid, bias2, h2, 0);

  // readout + head
  k_readout<<<(NN + 3) / 4, 256, 0, stream>>>(h2, gid, gsum, gcount);
  k_head<<<NG, 64, 0, stream>>>(gsum, gcount, Wh1, bh1, Wh2, bh2, (float*)d_out);
}

// Round 2
// 804.995 us; speedup vs baseline: 1.9207x; 1.9207x over previous
//
#include <hip/hip_runtime.h>

#define NN 20000     // nodes
#define NE 320000    // edges
#define NG 64        // graphs
#define DIN 128
#define DH 64
#define NH 8
#define HD 512       // NH*DH
#define NC 32

// ---------------- input linear: [NN,128] @ [128,64] + b ----------------
__global__ __launch_bounds__(256) void k_gemm_in(const float* __restrict__ A,
    const float* __restrict__ W, const float* __restrict__ b, float* __restrict__ out) {
  __shared__ float As[16][DIN];
  int c = threadIdx.x & 63;
  int rg = threadIdx.x >> 6;           // 0..3
  int row0 = blockIdx.x * 16;
  for (int i = threadIdx.x; i < 16 * DIN; i += 256) {
    int r = i >> 7, k = i & 127;
    int gr = row0 + r;
    As[r][k] = (gr < NN) ? A[gr * DIN + k] : 0.f;
  }
  __syncthreads();
  float acc[4] = {0.f, 0.f, 0.f, 0.f};
  for (int k = 0; k < DIN; ++k) {
    float w = W[k * DH + c];
#pragma unroll
    for (int i = 0; i < 4; ++i) acc[i] += As[rg * 4 + i][k] * w;
  }
  float bias = b[c];
#pragma unroll
  for (int i = 0; i < 4; ++i) {
    int gr = row0 + rg * 4 + i;
    if (gr < NN) out[gr * DH + c] = acc[i] + bias;
  }
}

// ---------------- hidden linear: [NN,64] @ [64,512] + b ----------------
__global__ __launch_bounds__(512) void k_gemm_h512(const float* __restrict__ A,
    const float* __restrict__ W, const float* __restrict__ b, float* __restrict__ out) {
  __shared__ float As[16][DH];
  int c = threadIdx.x;                 // 0..511
  int row0 = blockIdx.x * 16;
  for (int i = threadIdx.x; i < 16 * DH; i += 512) {
    int r = i >> 6, k = i & 63;
    int gr = row0 + r;
    As[r][k] = (gr < NN) ? A[gr * DH + k] : 0.f;
  }
  __syncthreads();
  float acc[16];
#pragma unroll
  for (int i = 0; i < 16; ++i) acc[i] = 0.f;
  for (int k = 0; k < DH; ++k) {
    float w = W[k * HD + c];
#pragma unroll
    for (int i = 0; i < 16; ++i) acc[i] += As[i][k] * w;
  }
  float bias = b[c];
#pragma unroll
  for (int i = 0; i < 16; ++i) {
    int gr = row0 + i;
    if (gr < NN) out[gr * HD + c] = acc[i] + bias;
  }
}

// ---------------- CSR build ----------------
__global__ void k_hist(const int* __restrict__ dst, int* __restrict__ counts) {
  int e = blockIdx.x * blockDim.x + threadIdx.x;
  if (e < NE) atomicAdd(&counts[dst[e]], 1);
}

__global__ __launch_bounds__(1024) void k_scan(const int* __restrict__ counts,
    int* __restrict__ row_start, int* __restrict__ cursor) {
  __shared__ int partial[1024];
  const int CH = (NN + 1023) / 1024;   // 20
  int t = threadIdx.x;
  int base = t * CH;
  int s = 0;
  for (int i = 0; i < CH; ++i) {
    int idx = base + i;
    if (idx < NN) s += counts[idx];
  }
  partial[t] = s;
  __syncthreads();
  for (int off = 1; off < 1024; off <<= 1) {
    int v = (t >= off) ? partial[t - off] : 0;
    __syncthreads();
    partial[t] += v;
    __syncthreads();
  }
  int prefix = (t > 0) ? partial[t - 1] : 0;
  for (int i = 0; i < CH; ++i) {
    int idx = base + i;
    if (idx < NN) {
      row_start[idx] = prefix;
      cursor[idx] = prefix;
      prefix += counts[idx];
    }
  }
  if (t == 1023) row_start[NN] = partial[1023];
}

// scatter src node ids directly into CSR slots (removes eid indirection)
__global__ void k_scatter(const int* __restrict__ dst, const int* __restrict__ src,
                          int* __restrict__ cursor, int* __restrict__ src_sorted) {
  int e = blockIdx.x * blockDim.x + threadIdx.x;
  if (e < NE) {
    int p = atomicAdd(&cursor[dst[e]], 1);
    src_sorted[p] = src[e];
  }
}

// ---------------- fused GATv2 layer: scores + online softmax + aggregate + mean ----
// one block per node, 8 waves = 8 heads, lane = feature dim
__global__ __launch_bounds__(512) void k_gat_fused(const float* __restrict__ fs,
    const float* __restrict__ fd, const int* __restrict__ src_sorted,
    const int* __restrict__ row_start, const float* __restrict__ attn,
    const float* __restrict__ bias, float* __restrict__ hout, int do_relu) {
  int v = blockIdx.x;
  int h = threadIdx.x >> 6, lane = threadIdx.x & 63;
  int hoff = h * DH;
  float fdv = fd[(size_t)v * HD + hoff + lane];
  float av = attn[hoff + lane];
  int beg = row_start[v], end = row_start[v + 1];
  float m = -3.4e38f, sum = 0.f, acc = 0.f;
  int j = beg;
  for (; j + 1 < end; j += 2) {
    int s0 = src_sorted[j], s1 = src_sorted[j + 1];
    float f0 = fs[(size_t)s0 * HD + hoff + lane];
    float f1 = fs[(size_t)s1 * HD + hoff + lane];
    float x0 = f0 + fdv; x0 = (x0 > 0.f) ? x0 : 0.2f * x0;
    float x1 = f1 + fdv; x1 = (x1 > 0.f) ? x1 : 0.2f * x1;
    float p0 = av * x0, p1 = av * x1;
#pragma unroll
    for (int off = 32; off > 0; off >>= 1) {
      p0 += __shfl_xor(p0, off, 64);
      p1 += __shfl_xor(p1, off, 64);
    }
    float mn = fmaxf(m, fmaxf(p0, p1));
    float scale = __expf(m - mn);
    float w0 = __expf(p0 - mn), w1 = __expf(p1 - mn);
    acc = acc * scale + w0 * f0 + w1 * f1;
    sum = sum * scale + w0 + w1;
    m = mn;
  }
  if (j < end) {
    int s0 = src_sorted[j];
    float f0 = fs[(size_t)s0 * HD + hoff + lane];
    float x0 = f0 + fdv; x0 = (x0 > 0.f) ? x0 : 0.2f * x0;
    float p0 = av * x0;
#pragma unroll
    for (int off = 32; off > 0; off >>= 1) p0 += __shfl_xor(p0, off, 64);
    float mn = fmaxf(m, p0);
    float scale = __expf(m - mn);
    float w0 = __expf(p0 - mn);
    acc = acc * scale + w0 * f0;
    sum = sum * scale + w0;
    m = mn;
  }
  __shared__ float sh[NH * DH];
  sh[threadIdx.x] = acc / fmaxf(sum, 1e-9f) + bias[hoff + lane];
  __syncthreads();
  if (threadIdx.x < DH) {
    float s = 0.f;
#pragma unroll
    for (int hh = 0; hh < NH; ++hh) s += sh[hh * DH + threadIdx.x];
    s *= (1.f / NH);
    if (do_relu) s = fmaxf(s, 0.f);
    hout[v * DH + threadIdx.x] = s;
  }
}

// ---------------- graph mean readout (accumulate) ----------------
__global__ __launch_bounds__(256) void k_readout(const float* __restrict__ h,
    const int* __restrict__ gid, float* __restrict__ gsum, int* __restrict__ gcount) {
  int wid = (blockIdx.x * 256 + threadIdx.x) >> 6;
  int lane = threadIdx.x & 63;
  if (wid >= NN) return;
  int g = gid[wid];
  atomicAdd(&gsum[g * DH + lane], h[wid * DH + lane]);
  if (lane == 0) atomicAdd(&gcount[g], 1);
}

// ---------------- classification head, one block per graph ----------------
__global__ __launch_bounds__(64) void k_head(const float* __restrict__ gsum,
    const int* __restrict__ gcount, const float* __restrict__ Wh1,
    const float* __restrict__ bh1, const float* __restrict__ Wh2,
    const float* __restrict__ bh2, float* __restrict__ out) {
  int g = blockIdx.x;
  int t = threadIdx.x;  // 64
  __shared__ float hg[DH];
  __shared__ float hid[DH];
  __shared__ float logits[NC];
  float cnt = fmaxf((float)gcount[g], 1.0f);
  hg[t] = gsum[g * DH + t] / cnt;
  __syncthreads();
  float a = 0.f;
  for (int k = 0; k < DH; ++k) a += hg[k] * Wh1[k * DH + t];
  hid[t] = fmaxf(a + bh1[t], 0.f);
  __syncthreads();
  if (t < NC) {
    float l = 0.f;
    for (int k = 0; k < DH; ++k) l += hid[k] * Wh2[k * NC + t];
    logits[t] = l + bh2[t];
  }
  __syncthreads();
  if (t == 0) {
    float mx = logits[0];
    for (int i = 1; i < NC; ++i) mx = fmaxf(mx, logits[i]);
    float s = 0.f;
    for (int i = 0; i < NC; ++i) {
      float w = __expf(logits[i] - mx);
      logits[i] = w;
      s += w;
    }
    float inv = 1.f / s;
    for (int i = 0; i < NC; ++i) out[g * NC + i] = logits[i] * inv;
  }
}

extern "C" void kernel_launch(void* const* d_in, const int* in_sizes, int n_in,
                              void* d_out, int out_size, void* d_ws, size_t ws_size,
                              hipStream_t stream) {
  const float* g_feats = (const float*)d_in[0];
  const int*   src     = (const int*)d_in[1];
  const int*   dst     = (const int*)d_in[2];
  const int*   gid     = (const int*)d_in[3];
  const float* W_in    = (const float*)d_in[4];
  const float* b_in    = (const float*)d_in[5];
  const float* Wsrc1   = (const float*)d_in[6];
  const float* bsrc1   = (const float*)d_in[7];
  const float* Wdst1   = (const float*)d_in[8];
  const float* bdst1   = (const float*)d_in[9];
  const float* attn1   = (const float*)d_in[10];
  const float* bias1   = (const float*)d_in[11];
  const float* Wsrc2   = (const float*)d_in[12];
  const float* bsrc2   = (const float*)d_in[13];
  const float* Wdst2   = (const float*)d_in[14];
  const float* bdst2   = (const float*)d_in[15];
  const float* attn2   = (const float*)d_in[16];
  const float* bias2   = (const float*)d_in[17];
  const float* Wh1     = (const float*)d_in[18];
  const float* bh1     = (const float*)d_in[19];
  const float* Wh2     = (const float*)d_in[20];
  const float* bh2     = (const float*)d_in[21];

  char* ws = (char*)d_ws;
  size_t off = 0;
  auto A = [&](size_t bytes) -> char* {
    char* p = ws + off;
    off = (off + bytes + 255) & ~(size_t)255;
    return p;
  };
  float* h0     = (float*)A((size_t)NN * DH * 4);
  float* h1     = (float*)A((size_t)NN * DH * 4);
  float* h2     = (float*)A((size_t)NN * DH * 4);
  float* fs     = (float*)A((size_t)NN * HD * 4);
  float* fd     = (float*)A((size_t)NN * HD * 4);
  int*   row_start  = (int*)A((size_t)(NN + 1) * 4);
  int*   cursor     = (int*)A((size_t)NN * 4);
  int*   src_sorted = (int*)A((size_t)NE * 4);
  // zero region: counts, gcount, gsum contiguous
  char*  zero_base = A((size_t)NN * 4);           // counts
  int*   counts    = (int*)zero_base;
  int*   gcount    = (int*)A((size_t)NG * 4);
  float* gsum      = (float*)A((size_t)NG * DH * 4);
  size_t zero_span = (size_t)((char*)gsum + (size_t)NG * DH * 4 - zero_base);

  hipMemsetAsync(zero_base, 0, zero_span, stream);

  k_gemm_in<<<(NN + 15) / 16, 256, 0, stream>>>(g_feats, W_in, b_in, h0);
  k_hist<<<(NE + 255) / 256, 256, 0, stream>>>(dst, counts);
  k_scan<<<1, 1024, 0, stream>>>(counts, row_start, cursor);
  k_scatter<<<(NE + 255) / 256, 256, 0, stream>>>(dst, src, cursor, src_sorted);

  // layer 1
  k_gemm_h512<<<(NN + 15) / 16, 512, 0, stream>>>(h0, Wsrc1, bsrc1, fs);
  k_gemm_h512<<<(NN + 15) / 16, 512, 0, stream>>>(h0, Wdst1, bdst1, fd);
  k_gat_fused<<<NN, 512, 0, stream>>>(fs, fd, src_sorted, row_start, attn1, bias1, h1, 1);

  // layer 2
  k_gemm_h512<<<(NN + 15) / 16, 512, 0, stream>>>(h1, Wsrc2, bsrc2, fs);
  k_gemm_h512<<<(NN + 15) / 16, 512, 0, stream>>>(h1, Wdst2, bdst2, fd);
  k_gat_fused<<<NN, 512, 0, stream>>>(fs, fd, src_sorted, row_start, attn2, bias2, h2, 0);

  // readout + head
  k_readout<<<(NN + 3) / 4, 256, 0, stream>>>(h2, gid, gsum, gcount);
  k_head<<<NG, 64, 0, stream>>>(gsum, gcount, Wh1, bh1, Wh2, bh2, (float*)d_out);
}

// Round 3
// 620.490 us; speedup vs baseline: 2.4918x; 1.2974x over previous
//
#include <hip/hip_runtime.h>

#define NN 20000     // nodes
#define NE 320000    // edges
#define NG 64        // graphs
#define DIN 128
#define DH 64
#define NH 8
#define HD 512       // NH*DH
#define NC 32

typedef unsigned short ushort_t;
typedef unsigned int uint_t;

__device__ __forceinline__ ushort_t f2bf(float f) {   // RNE float->bf16
  uint_t x = __float_as_uint(f);
  uint_t r = (x + 0x7fffu + ((x >> 16) & 1u)) >> 16;
  return (ushort_t)r;
}

// ---------------- input linear: [NN,128] @ [128,64] + b ----------------
__global__ __launch_bounds__(256) void k_gemm_in(const float* __restrict__ A,
    const float* __restrict__ W, const float* __restrict__ b, float* __restrict__ out) {
  __shared__ float As[16][DIN];
  int c = threadIdx.x & 63;
  int rg = threadIdx.x >> 6;           // 0..3
  int row0 = blockIdx.x * 16;
  for (int i = threadIdx.x; i < 16 * DIN; i += 256) {
    int r = i >> 7, k = i & 127;
    int gr = row0 + r;
    As[r][k] = (gr < NN) ? A[gr * DIN + k] : 0.f;
  }
  __syncthreads();
  float acc[4] = {0.f, 0.f, 0.f, 0.f};
  for (int k = 0; k < DIN; ++k) {
    float w = W[k * DH + c];
#pragma unroll
    for (int i = 0; i < 4; ++i) acc[i] += As[rg * 4 + i][k] * w;
  }
  float bias = b[c];
#pragma unroll
  for (int i = 0; i < 4; ++i) {
    int gr = row0 + rg * 4 + i;
    if (gr < NN) out[gr * DH + c] = acc[i] + bias;
  }
}

// ---------------- hidden linear: [NN,64] @ [64,512] + b, 4x4 reg tile ----------
// BF16OUT: pack output to bf16 (for fs); else fp32 (for fd)
template<bool BF16OUT>
__global__ __launch_bounds__(512) void k_gemm64(const float* __restrict__ A,
    const float* __restrict__ W, const float* __restrict__ b,
    float* __restrict__ outf, ushort_t* __restrict__ outb) {
  __shared__ float As[16][DH];
  int tc = threadIdx.x & 127;          // col quad: cols 4tc..4tc+3
  int tr = threadIdx.x >> 7;           // 0..3 -> rows tr*4..tr*4+3
  int row0 = blockIdx.x * 16;
  for (int i = threadIdx.x; i < 16 * DH; i += 512) {
    int r = i >> 6, k = i & 63;
    int gr = row0 + r;
    As[r][k] = (gr < NN) ? A[gr * DH + k] : 0.f;
  }
  __syncthreads();
  float acc[4][4];
#pragma unroll
  for (int r = 0; r < 4; ++r)
#pragma unroll
    for (int c = 0; c < 4; ++c) acc[r][c] = 0.f;
#pragma unroll 4
  for (int k = 0; k < DH; ++k) {
    float4 wv = *(const float4*)&W[k * HD + 4 * tc];
    float a0 = As[tr * 4 + 0][k];
    float a1 = As[tr * 4 + 1][k];
    float a2 = As[tr * 4 + 2][k];
    float a3 = As[tr * 4 + 3][k];
    acc[0][0] += a0 * wv.x; acc[0][1] += a0 * wv.y; acc[0][2] += a0 * wv.z; acc[0][3] += a0 * wv.w;
    acc[1][0] += a1 * wv.x; acc[1][1] += a1 * wv.y; acc[1][2] += a1 * wv.z; acc[1][3] += a1 * wv.w;
    acc[2][0] += a2 * wv.x; acc[2][1] += a2 * wv.y; acc[2][2] += a2 * wv.z; acc[2][3] += a2 * wv.w;
    acc[3][0] += a3 * wv.x; acc[3][1] += a3 * wv.y; acc[3][2] += a3 * wv.z; acc[3][3] += a3 * wv.w;
  }
  float4 bv = *(const float4*)&b[4 * tc];
#pragma unroll
  for (int r = 0; r < 4; ++r) {
    int row = row0 + tr * 4 + r;
    if (row >= NN) continue;
    float v0 = acc[r][0] + bv.x, v1 = acc[r][1] + bv.y;
    float v2 = acc[r][2] + bv.z, v3 = acc[r][3] + bv.w;
    if (BF16OUT) {
      ushort4 o;
      o.x = f2bf(v0); o.y = f2bf(v1); o.z = f2bf(v2); o.w = f2bf(v3);
      *(ushort4*)&outb[(size_t)row * HD + 4 * tc] = o;
    } else {
      *(float4*)&outf[(size_t)row * HD + 4 * tc] = make_float4(v0, v1, v2, v3);
    }
  }
}

// ---------------- CSR build ----------------
__global__ void k_hist(const int* __restrict__ dst, int* __restrict__ counts) {
  int e = blockIdx.x * blockDim.x + threadIdx.x;
  if (e < NE) atomicAdd(&counts[dst[e]], 1);
}

__global__ __launch_bounds__(1024) void k_scan(const int* __restrict__ counts,
    int* __restrict__ row_start, int* __restrict__ cursor) {
  __shared__ int partial[1024];
  const int CH = (NN + 1023) / 1024;   // 20
  int t = threadIdx.x;
  int base = t * CH;
  int s = 0;
  for (int i = 0; i < CH; ++i) {
    int idx = base + i;
    if (idx < NN) s += counts[idx];
  }
  partial[t] = s;
  __syncthreads();
  for (int off = 1; off < 1024; off <<= 1) {
    int v = (t >= off) ? partial[t - off] : 0;
    __syncthreads();
    partial[t] += v;
    __syncthreads();
  }
  int prefix = (t > 0) ? partial[t - 1] : 0;
  for (int i = 0; i < CH; ++i) {
    int idx = base + i;
    if (idx < NN) {
      row_start[idx] = prefix;
      cursor[idx] = prefix;
      prefix += counts[idx];
    }
  }
  if (t == 1023) row_start[NN] = partial[1023];
}

__global__ void k_scatter(const int* __restrict__ dst, const int* __restrict__ src,
                          int* __restrict__ cursor, int* __restrict__ src_sorted) {
  int e = blockIdx.x * blockDim.x + threadIdx.x;
  if (e < NE) {
    int p = atomicAdd(&cursor[dst[e]], 1);
    src_sorted[p] = src[e];
  }
}

// graph boundaries from sorted gid
__global__ void k_gbound(const int* __restrict__ gid, int* __restrict__ gs) {
  int i = blockIdx.x * blockDim.x + threadIdx.x;
  if (i > NN) return;
  if (i == 0) {
    for (int g = 0; g <= gid[0]; ++g) gs[g] = 0;
  } else if (i == NN) {
    for (int g = gid[NN - 1] + 1; g <= NG; ++g) gs[g] = NN;
  } else {
    int a = gid[i - 1], b2 = gid[i];
    for (int g = a + 1; g <= b2; ++g) gs[g] = i;
  }
}

// ------- fused GATv2: scores + online softmax + aggregate + head-mean ----------
// block = node, 8 waves = 8 heads; half-wave = one edge; lane owns 2 features.
__global__ __launch_bounds__(512) void k_gat_fused(const ushort_t* __restrict__ fsb,
    const float* __restrict__ fd, const int* __restrict__ src_sorted,
    const int* __restrict__ row_start, const float* __restrict__ attn,
    const float* __restrict__ bias, float* __restrict__ hout, int do_relu) {
  int v = blockIdx.x;
  int h = threadIdx.x >> 6;
  int lane = threadIdx.x & 63;
  int half = lane >> 5;                // which edge of the pair
  int sl = lane & 31;                  // sub-lane: features 2sl, 2sl+1
  int hoff = h * DH;
  int fi = hoff + 2 * sl;
  float2 fdv = *(const float2*)&fd[(size_t)v * HD + fi];
  float2 av = *(const float2*)&attn[fi];
  int beg = row_start[v], end = row_start[v + 1];
  float m = -3.4e38f, sum = 0.f, acc0 = 0.f, acc1 = 0.f;
  for (int j = beg; j < end; j += 4) {
    int eA = j + half;
    int eB = j + 2 + half;
    bool vA = eA < end, vB = eB < end;
    int sA = src_sorted[vA ? eA : beg];
    int sB = src_sorted[vB ? eB : beg];
    uint_t uA = *(const uint_t*)&fsb[(size_t)sA * HD + fi];
    uint_t uB = *(const uint_t*)&fsb[(size_t)sB * HD + fi];
    float fA0 = __uint_as_float(uA << 16);
    float fA1 = __uint_as_float(uA & 0xffff0000u);
    float fB0 = __uint_as_float(uB << 16);
    float fB1 = __uint_as_float(uB & 0xffff0000u);
    float xA0 = fA0 + fdv.x; xA0 = (xA0 > 0.f) ? xA0 : 0.2f * xA0;
    float xA1 = fA1 + fdv.y; xA1 = (xA1 > 0.f) ? xA1 : 0.2f * xA1;
    float xB0 = fB0 + fdv.x; xB0 = (xB0 > 0.f) ? xB0 : 0.2f * xB0;
    float xB1 = fB1 + fdv.y; xB1 = (xB1 > 0.f) ? xB1 : 0.2f * xB1;
    float pA = av.x * xA0 + av.y * xA1;
    float pB = av.x * xB0 + av.y * xB1;
#pragma unroll
    for (int off = 1; off < 32; off <<= 1) {
      pA += __shfl_xor(pA, off);
      pB += __shfl_xor(pB, off);
    }
    if (!vA) pA = -3.4e38f;
    if (!vB) pB = -3.4e38f;
    float mn = fmaxf(m, fmaxf(pA, pB));
    float scale = __expf(m - mn);
    float wA = __expf(pA - mn);
    float wB = __expf(pB - mn);
    acc0 = acc0 * scale + wA * fA0 + wB * fB0;
    acc1 = acc1 * scale + wA * fA1 + wB * fB1;
    sum = sum * scale + wA + wB;
    m = mn;
  }
  // merge the two half-wave states
  float mo = __shfl_xor(m, 32);
  float sumo = __shfl_xor(sum, 32);
  float a0o = __shfl_xor(acc0, 32);
  float a1o = __shfl_xor(acc1, 32);
  float M = fmaxf(m, mo);
  float sSelf = __expf(m - M), sOth = __expf(mo - M);
  acc0 = acc0 * sSelf + a0o * sOth;
  acc1 = acc1 * sSelf + a1o * sOth;
  sum = sum * sSelf + sumo * sOth;
  float inv = 1.f / fmaxf(sum, 1e-9f);
  __shared__ float sh[NH * DH];
  if (half == 0) {
    sh[hoff + 2 * sl]     = acc0 * inv + bias[fi];
    sh[hoff + 2 * sl + 1] = acc1 * inv + bias[fi + 1];
  }
  __syncthreads();
  if (threadIdx.x < DH) {
    float s = 0.f;
#pragma unroll
    for (int hh = 0; hh < NH; ++hh) s += sh[hh * DH + threadIdx.x];
    s *= (1.f / NH);
    if (do_relu) s = fmaxf(s, 0.f);
    hout[(size_t)v * DH + threadIdx.x] = s;
  }
}

// ---------------- per-graph mean + MLP head + softmax ----------------
__global__ __launch_bounds__(64) void k_head(const float* __restrict__ h2,
    const int* __restrict__ gs, const float* __restrict__ Wh1,
    const float* __restrict__ bh1, const float* __restrict__ Wh2,
    const float* __restrict__ bh2, float* __restrict__ out) {
  int g = blockIdx.x;
  int t = threadIdx.x;  // 64
  __shared__ float hg[DH];
  __shared__ float hid[DH];
  __shared__ float logits[NC];
  int start = gs[g], stop = gs[g + 1];
  float s = 0.f;
  for (int r = start; r < stop; ++r) s += h2[(size_t)r * DH + t];
  hg[t] = s / fmaxf((float)(stop - start), 1.f);
  __syncthreads();
  float a = 0.f;
  for (int k = 0; k < DH; ++k) a += hg[k] * Wh1[k * DH + t];
  hid[t] = fmaxf(a + bh1[t], 0.f);
  __syncthreads();
  if (t < NC) {
    float l = 0.f;
    for (int k = 0; k < DH; ++k) l += hid[k] * Wh2[k * NC + t];
    logits[t] = l + bh2[t];
  }
  __syncthreads();
  if (t == 0) {
    float mx = logits[0];
    for (int i = 1; i < NC; ++i) mx = fmaxf(mx, logits[i]);
    float sm = 0.f;
    for (int i = 0; i < NC; ++i) {
      float w = __expf(logits[i] - mx);
      logits[i] = w;
      sm += w;
    }
    float inv = 1.f / sm;
    for (int i = 0; i < NC; ++i) out[g * NC + i] = logits[i] * inv;
  }
}

extern "C" void kernel_launch(void* const* d_in, const int* in_sizes, int n_in,
                              void* d_out, int out_size, void* d_ws, size_t ws_size,
                              hipStream_t stream) {
  const float* g_feats = (const float*)d_in[0];
  const int*   src     = (const int*)d_in[1];
  const int*   dst     = (const int*)d_in[2];
  const int*   gid     = (const int*)d_in[3];
  const float* W_in    = (const float*)d_in[4];
  const float* b_in    = (const float*)d_in[5];
  const float* Wsrc1   = (const float*)d_in[6];
  const float* bsrc1   = (const float*)d_in[7];
  const float* Wdst1   = (const float*)d_in[8];
  const float* bdst1   = (const float*)d_in[9];
  const float* attn1   = (const float*)d_in[10];
  const float* bias1   = (const float*)d_in[11];
  const float* Wsrc2   = (const float*)d_in[12];
  const float* bsrc2   = (const float*)d_in[13];
  const float* Wdst2   = (const float*)d_in[14];
  const float* bdst2   = (const float*)d_in[15];
  const float* attn2   = (const float*)d_in[16];
  const float* bias2   = (const float*)d_in[17];
  const float* Wh1     = (const float*)d_in[18];
  const float* bh1     = (const float*)d_in[19];
  const float* Wh2     = (const float*)d_in[20];
  const float* bh2     = (const float*)d_in[21];

  char* ws = (char*)d_ws;
  size_t off = 0;
  auto A = [&](size_t bytes) -> char* {
    char* p = ws + off;
    off = (off + bytes + 255) & ~(size_t)255;
    return p;
  };
  float*    h0         = (float*)A((size_t)NN * DH * 4);
  float*    h1         = (float*)A((size_t)NN * DH * 4);
  float*    h2         = (float*)A((size_t)NN * DH * 4);
  ushort_t* fsb        = (ushort_t*)A((size_t)NN * HD * 2);
  float*    fd         = (float*)A((size_t)NN * HD * 4);
  int*      row_start  = (int*)A((size_t)(NN + 1) * 4);
  int*      cursor     = (int*)A((size_t)NN * 4);
  int*      src_sorted = (int*)A((size_t)NE * 4);
  int*      gs         = (int*)A((size_t)(NG + 1) * 4);
  int*      counts     = (int*)A((size_t)NN * 4);   // must be zeroed

  hipMemsetAsync(counts, 0, (size_t)NN * 4, stream);

  k_gemm_in<<<(NN + 15) / 16, 256, 0, stream>>>(g_feats, W_in, b_in, h0);
  k_hist<<<(NE + 255) / 256, 256, 0, stream>>>(dst, counts);
  k_scan<<<1, 1024, 0, stream>>>(counts, row_start, cursor);
  k_scatter<<<(NE + 255) / 256, 256, 0, stream>>>(dst, src, cursor, src_sorted);
  k_gbound<<<(NN + 256) / 256, 256, 0, stream>>>(gid, gs);

  // layer 1
  k_gemm64<true ><<<(NN + 15) / 16, 512, 0, stream>>>(h0, Wsrc1, bsrc1, nullptr, fsb);
  k_gemm64<false><<<(NN + 15) / 16, 512, 0, stream>>>(h0, Wdst1, bdst1, fd, nullptr);
  k_gat_fused<<<NN, 512, 0, stream>>>(fsb, fd, src_sorted, row_start, attn1, bias1, h1, 1);

  // layer 2
  k_gemm64<true ><<<(NN + 15) / 16, 512, 0, stream>>>(h1, Wsrc2, bsrc2, nullptr, fsb);
  k_gemm64<false><<<(NN + 15) / 16, 512, 0, stream>>>(h1, Wdst2, bdst2, fd, nullptr);
  k_gat_fused<<<NN, 512, 0, stream>>>(fsb, fd, src_sorted, row_start, attn2, bias2, h2, 0);

  // readout + head
  k_head<<<NG, 64, 0, stream>>>(h2, gs, Wh1, bh1, Wh2, bh2, (float*)d_out);
}

// Round 6
// 479.297 us; speedup vs baseline: 3.2258x; 1.2946x over previous
//
#include <hip/hip_runtime.h>

#define NN 20000     // nodes
#define NE 320000    // edges
#define NG 64        // graphs
#define DIN 128
#define DH 64
#define NH 8
#define HD 512       // NH*DH
#define NC 32

typedef unsigned short ushort_t;
typedef unsigned int uint_t;

__device__ __forceinline__ ushort_t f2bf(float f) {   // RNE float->bf16
  uint_t x = __float_as_uint(f);
  uint_t r = (x + 0x7fffu + ((x >> 16) & 1u)) >> 16;
  return (ushort_t)r;
}

template<int PAT>
__device__ __forceinline__ float swz(float v) {
  return __int_as_float(__builtin_amdgcn_ds_swizzle(__float_as_int(v), PAT));
}

// ------- input linear: [NN,128] @ [128,64] + b; blocks 0-19 also zero counts ----
__global__ __launch_bounds__(256) void k_gemm_in(const float* __restrict__ A,
    const float* __restrict__ W, const float* __restrict__ b, float* __restrict__ out,
    int* __restrict__ counts) {
  if (blockIdx.x < 20) {
    for (int i = threadIdx.x; i < 1000; i += 256) counts[blockIdx.x * 1000 + i] = 0;
  }
  __shared__ float As[16][DIN];
  int c = threadIdx.x & 63;
  int rg = threadIdx.x >> 6;           // 0..3
  int row0 = blockIdx.x * 16;
  for (int i = threadIdx.x; i < 16 * DIN; i += 256) {
    int r = i >> 7, k = i & 127;
    int gr = row0 + r;
    As[r][k] = (gr < NN) ? A[gr * DIN + k] : 0.f;
  }
  __syncthreads();
  float acc[4] = {0.f, 0.f, 0.f, 0.f};
  for (int k = 0; k < DIN; ++k) {
    float w = W[k * DH + c];
#pragma unroll
    for (int i = 0; i < 4; ++i) acc[i] += As[rg * 4 + i][k] * w;
  }
  float bias = b[c];
#pragma unroll
  for (int i = 0; i < 4; ++i) {
    int gr = row0 + rg * 4 + i;
    if (gr < NN) out[gr * DH + c] = acc[i] + bias;
  }
}

// ------- hidden linear pair: computes fs(bf16) and fd(fp32) in one dispatch -----
__global__ __launch_bounds__(512) void k_gemm64pair(const float* __restrict__ A,
    const float* __restrict__ Wsrc, const float* __restrict__ bsrc,
    const float* __restrict__ Wdst, const float* __restrict__ bdst,
    ushort_t* __restrict__ fsb, float* __restrict__ fd) {
  const int nb = (NN + 15) / 16;       // 1250
  bool isFd = blockIdx.x >= nb;
  int bx = isFd ? (blockIdx.x - nb) : blockIdx.x;
  const float* W = isFd ? Wdst : Wsrc;
  const float* b = isFd ? bdst : bsrc;
  __shared__ float As[16][DH];
  int tc = threadIdx.x & 127;          // col quad: cols 4tc..4tc+3
  int tr = threadIdx.x >> 7;           // 0..3 -> rows tr*4..tr*4+3
  int row0 = bx * 16;
  for (int i = threadIdx.x; i < 16 * DH; i += 512) {
    int r = i >> 6, k = i & 63;
    int gr = row0 + r;
    As[r][k] = (gr < NN) ? A[gr * DH + k] : 0.f;
  }
  __syncthreads();
  float acc[4][4];
#pragma unroll
  for (int r = 0; r < 4; ++r)
#pragma unroll
    for (int c = 0; c < 4; ++c) acc[r][c] = 0.f;
#pragma unroll 4
  for (int k = 0; k < DH; ++k) {
    float4 wv = *(const float4*)&W[k * HD + 4 * tc];
    float a0 = As[tr * 4 + 0][k];
    float a1 = As[tr * 4 + 1][k];
    float a2 = As[tr * 4 + 2][k];
    float a3 = As[tr * 4 + 3][k];
    acc[0][0] += a0 * wv.x; acc[0][1] += a0 * wv.y; acc[0][2] += a0 * wv.z; acc[0][3] += a0 * wv.w;
    acc[1][0] += a1 * wv.x; acc[1][1] += a1 * wv.y; acc[1][2] += a1 * wv.z; acc[1][3] += a1 * wv.w;
    acc[2][0] += a2 * wv.x; acc[2][1] += a2 * wv.y; acc[2][2] += a2 * wv.z; acc[2][3] += a2 * wv.w;
    acc[3][0] += a3 * wv.x; acc[3][1] += a3 * wv.y; acc[3][2] += a3 * wv.z; acc[3][3] += a3 * wv.w;
  }
  float4 bv = *(const float4*)&b[4 * tc];
#pragma unroll
  for (int r = 0; r < 4; ++r) {
    int row = row0 + tr * 4 + r;
    if (row >= NN) continue;
    float v0 = acc[r][0] + bv.x, v1 = acc[r][1] + bv.y;
    float v2 = acc[r][2] + bv.z, v3 = acc[r][3] + bv.w;
    if (!isFd) {
      ushort4 o;
      o.x = f2bf(v0); o.y = f2bf(v1); o.z = f2bf(v2); o.w = f2bf(v3);
      *(ushort4*)&fsb[(size_t)row * HD + 4 * tc] = o;
    } else {
      *(float4*)&fd[(size_t)row * HD + 4 * tc] = make_float4(v0, v1, v2, v3);
    }
  }
}

// ---------------- CSR build ----------------
__global__ void k_hist(const int* __restrict__ dst, int* __restrict__ counts) {
  int e = blockIdx.x * blockDim.x + threadIdx.x;
  if (e < NE) atomicAdd(&counts[dst[e]], 1);
}

// block 0: exclusive scan of counts -> row_start/cursor; blocks 1..20: gbound
__global__ __launch_bounds__(1024) void k_scan_gbound(const int* __restrict__ counts,
    int* __restrict__ row_start, int* __restrict__ cursor,
    const int* __restrict__ gid, int* __restrict__ gs) {
  if (blockIdx.x > 0) {
    int i = (blockIdx.x - 1) * 1024 + threadIdx.x;
    if (i > NN) return;
    if (i == 0) {
      for (int g = 0; g <= gid[0]; ++g) gs[g] = 0;
    } else if (i == NN) {
      for (int g = gid[NN - 1] + 1; g <= NG; ++g) gs[g] = NN;
    } else {
      int a = gid[i - 1], b2 = gid[i];
      for (int g = a + 1; g <= b2; ++g) gs[g] = i;
    }
    return;
  }
  __shared__ int partial[1024];
  const int CH = (NN + 1023) / 1024;   // 20
  int t = threadIdx.x;
  int base = t * CH;
  int s = 0;
  for (int i = 0; i < CH; ++i) {
    int idx = base + i;
    if (idx < NN) s += counts[idx];
  }
  partial[t] = s;
  __syncthreads();
  for (int off = 1; off < 1024; off <<= 1) {
    int v = (t >= off) ? partial[t - off] : 0;
    __syncthreads();
    partial[t] += v;
    __syncthreads();
  }
  int prefix = (t > 0) ? partial[t - 1] : 0;
  for (int i = 0; i < CH; ++i) {
    int idx = base + i;
    if (idx < NN) {
      row_start[idx] = prefix;
      cursor[idx] = prefix;
      prefix += counts[idx];
    }
  }
  if (t == 1023) row_start[NN] = partial[1023];
}

__global__ void k_scatter(const int* __restrict__ dst, const int* __restrict__ src,
                          int* __restrict__ cursor, int* __restrict__ src_sorted) {
  int e = blockIdx.x * blockDim.x + threadIdx.x;
  if (e < NE) {
    int p = atomicAdd(&cursor[dst[e]], 1);
    src_sorted[p] = src[e];
  }
}

// ------- fused GATv2: scores + online softmax + aggregate + head-mean ----------
// block = node, 8 waves = 8 heads; 16 lanes per edge (4 bf16 features per lane);
// 4 quarter-wave groups x 2 sequential edges = 8 edges per wave-iteration.
__global__ __launch_bounds__(512) void k_gat_fused(const ushort_t* __restrict__ fsb,
    const float* __restrict__ fd, const int* __restrict__ src_sorted,
    const int* __restrict__ row_start, const float* __restrict__ attn,
    const float* __restrict__ bias, float* __restrict__ hout, int do_relu) {
  int v = blockIdx.x;
  int h = threadIdx.x >> 6;
  int lane = threadIdx.x & 63;
  int qw = lane >> 4;                  // quarter-wave: which edge of the group
  int sl = lane & 15;                  // sub-lane: features 4sl..4sl+3
  int hoff = h * DH;
  int fi = hoff + 4 * sl;
  float4 fdv = *(const float4*)&fd[(size_t)v * HD + fi];
  float4 av = *(const float4*)&attn[fi];
  int beg = row_start[v], end = row_start[v + 1];
  float m = -3.4e38f, sum = 0.f;
  float acc0 = 0.f, acc1 = 0.f, acc2 = 0.f, acc3 = 0.f;
  for (int j = beg; j < end; j += 8) {
    int eA = j + qw;
    int eB = j + 4 + qw;
    bool vA = eA < end, vB = eB < end;
    int sA = src_sorted[vA ? eA : beg];
    int sB = src_sorted[vB ? eB : beg];
    uint2 uA = *(const uint2*)&fsb[(size_t)sA * HD + fi];
    uint2 uB = *(const uint2*)&fsb[(size_t)sB * HD + fi];
    float fA0 = __uint_as_float(uA.x << 16);
    float fA1 = __uint_as_float(uA.x & 0xffff0000u);
    float fA2 = __uint_as_float(uA.y << 16);
    float fA3 = __uint_as_float(uA.y & 0xffff0000u);
    float fB0 = __uint_as_float(uB.x << 16);
    float fB1 = __uint_as_float(uB.x & 0xffff0000u);
    float fB2 = __uint_as_float(uB.y << 16);
    float fB3 = __uint_as_float(uB.y & 0xffff0000u);
    float xA0 = fA0 + fdv.x; xA0 = (xA0 > 0.f) ? xA0 : 0.2f * xA0;
    float xA1 = fA1 + fdv.y; xA1 = (xA1 > 0.f) ? xA1 : 0.2f * xA1;
    float xA2 = fA2 + fdv.z; xA2 = (xA2 > 0.f) ? xA2 : 0.2f * xA2;
    float xA3 = fA3 + fdv.w; xA3 = (xA3 > 0.f) ? xA3 : 0.2f * xA3;
    float xB0 = fB0 + fdv.x; xB0 = (xB0 > 0.f) ? xB0 : 0.2f * xB0;
    float xB1 = fB1 + fdv.y; xB1 = (xB1 > 0.f) ? xB1 : 0.2f * xB1;
    float xB2 = fB2 + fdv.z; xB2 = (xB2 > 0.f) ? xB2 : 0.2f * xB2;
    float xB3 = fB3 + fdv.w; xB3 = (xB3 > 0.f) ? xB3 : 0.2f * xB3;
    float pA = av.x * xA0 + av.y * xA1 + av.z * xA2 + av.w * xA3;
    float pB = av.x * xB0 + av.y * xB1 + av.z * xB2 + av.w * xB3;
    // 16-lane reduce via BitMode xor swizzle (1 DS inst per step)
    pA += swz<0x041F>(pA); pB += swz<0x041F>(pB);
    pA += swz<0x081F>(pA); pB += swz<0x081F>(pB);
    pA += swz<0x101F>(pA); pB += swz<0x101F>(pB);
    pA += swz<0x201F>(pA); pB += swz<0x201F>(pB);
    if (!vA) pA = -3.4e38f;
    if (!vB) pB = -3.4e38f;
    float mn = fmaxf(m, fmaxf(pA, pB));
    float scale = __expf(m - mn);
    float wA = __expf(pA - mn);
    float wB = __expf(pB - mn);
    acc0 = acc0 * scale + wA * fA0 + wB * fB0;
    acc1 = acc1 * scale + wA * fA1 + wB * fB1;
    acc2 = acc2 * scale + wA * fA2 + wB * fB2;
    acc3 = acc3 * scale + wA * fA3 + wB * fB3;
    sum = sum * scale + wA + wB;
    m = mn;
  }
  // merge the 4 quarter-wave states: xor-16 (swizzle) then xor-32 (shfl)
  {
    float mo = swz<0x401F>(m), so = swz<0x401F>(sum);
    float o0 = swz<0x401F>(acc0), o1 = swz<0x401F>(acc1);
    float o2 = swz<0x401F>(acc2), o3 = swz<0x401F>(acc3);
    float M = fmaxf(m, mo);
    float ea = __expf(m - M), eb = __expf(mo - M);
    acc0 = acc0 * ea + o0 * eb; acc1 = acc1 * ea + o1 * eb;
    acc2 = acc2 * ea + o2 * eb; acc3 = acc3 * ea + o3 * eb;
    sum = sum * ea + so * eb;
    m = M;
  }
  {
    float mo = __shfl_xor(m, 32), so = __shfl_xor(sum, 32);
    float o0 = __shfl_xor(acc0, 32), o1 = __shfl_xor(acc1, 32);
    float o2 = __shfl_xor(acc2, 32), o3 = __shfl_xor(acc3, 32);
    float M = fmaxf(m, mo);
    float ea = __expf(m - M), eb = __expf(mo - M);
    acc0 = acc0 * ea + o0 * eb; acc1 = acc1 * ea + o1 * eb;
    acc2 = acc2 * ea + o2 * eb; acc3 = acc3 * ea + o3 * eb;
    sum = sum * ea + so * eb;
  }
  float inv = 1.f / fmaxf(sum, 1e-9f);
  __shared__ float4 sh4[NH * 16];
  if (lane < 16) {
    float4 bv = *(const float4*)&bias[fi];
    sh4[h * 16 + sl] = make_float4(acc0 * inv + bv.x, acc1 * inv + bv.y,
                                   acc2 * inv + bv.z, acc3 * inv + bv.w);
  }
  __syncthreads();
  if (threadIdx.x < DH) {
    const float* shf = (const float*)sh4;
    float s = 0.f;
#pragma unroll
    for (int hh = 0; hh < NH; ++hh) s += shf[hh * DH + threadIdx.x];
    s *= (1.f / NH);
    if (do_relu) s = fmaxf(s, 0.f);
    hout[(size_t)v * DH + threadIdx.x] = s;
  }
}

// ---------------- per-graph mean + MLP head + softmax (256 thr) ----------------
__global__ __launch_bounds__(256) void k_head(const float* __restrict__ h2,
    const int* __restrict__ gs, const float* __restrict__ Wh1,
    const float* __restrict__ bh1, const float* __restrict__ Wh2,
    const float* __restrict__ bh2, float* __restrict__ out) {
  int g = blockIdx.x;
  int t = threadIdx.x;                 // 256
  int f = t & 63, chunk = t >> 6;      // 4 chunks
  __shared__ float part[4][DH];
  __shared__ float hg[DH];
  __shared__ float hid[DH];
  __shared__ float logits[NC];
  int start = gs[g], stop = gs[g + 1];
  float s = 0.f;
  for (int r = start + chunk; r < stop; r += 4) s += h2[(size_t)r * DH + f];
  part[chunk][f] = s;
  __syncthreads();
  if (t < DH) {
    float tot = part[0][t] + part[1][t] + part[2][t] + part[3][t];
    hg[t] = tot / fmaxf((float)(stop - start), 1.f);
  }
  __syncthreads();
  if (t < DH) {
    float a = 0.f;
    for (int k = 0; k < DH; ++k) a += hg[k] * Wh1[k * DH + t];
    hid[t] = fmaxf(a + bh1[t], 0.f);
  }
  __syncthreads();
  if (t < NC) {
    float l = 0.f;
    for (int k = 0; k < DH; ++k) l += hid[k] * Wh2[k * NC + t];
    logits[t] = l + bh2[t];
  }
  __syncthreads();
  if (t == 0) {
    float mx = logits[0];
    for (int i = 1; i < NC; ++i) mx = fmaxf(mx, logits[i]);
    float sm = 0.f;
    for (int i = 0; i < NC; ++i) {
      float w = __expf(logits[i] - mx);
      logits[i] = w;
      sm += w;
    }
    float invs = 1.f / sm;
    for (int i = 0; i < NC; ++i) out[g * NC + i] = logits[i] * invs;
  }
}

extern "C" void kernel_launch(void* const* d_in, const int* in_sizes, int n_in,
                              void* d_out, int out_size, void* d_ws, size_t ws_size,
                              hipStream_t stream) {
  const float* g_feats = (const float*)d_in[0];
  const int*   src     = (const int*)d_in[1];
  const int*   dst     = (const int*)d_in[2];
  const int*   gid     = (const int*)d_in[3];
  const float* W_in    = (const float*)d_in[4];
  const float* b_in    = (const float*)d_in[5];
  const float* Wsrc1   = (const float*)d_in[6];
  const float* bsrc1   = (const float*)d_in[7];
  const float* Wdst1   = (const float*)d_in[8];
  const float* bdst1   = (const float*)d_in[9];
  const float* attn1   = (const float*)d_in[10];
  const float* bias1   = (const float*)d_in[11];
  const float* Wsrc2   = (const float*)d_in[12];
  const float* bsrc2   = (const float*)d_in[13];
  const float* Wdst2   = (const float*)d_in[14];
  const float* bdst2   = (const float*)d_in[15];
  const float* attn2   = (const float*)d_in[16];
  const float* bias2   = (const float*)d_in[17];
  const float* Wh1     = (const float*)d_in[18];
  const float* bh1     = (const float*)d_in[19];
  const float* Wh2     = (const float*)d_in[20];
  const float* bh2     = (const float*)d_in[21];

  char* ws = (char*)d_ws;
  size_t off = 0;
  auto A = [&](size_t bytes) -> char* {
    char* p = ws + off;
    off = (off + bytes + 255) & ~(size_t)255;
    return p;
  };
  float*    h0         = (float*)A((size_t)NN * DH * 4);
  float*    h1         = (float*)A((size_t)NN * DH * 4);
  float*    h2         = (float*)A((size_t)NN * DH * 4);
  ushort_t* fsb        = (ushort_t*)A((size_t)NN * HD * 2);
  float*    fd         = (float*)A((size_t)NN * HD * 4);
  int*      row_start  = (int*)A((size_t)(NN + 1) * 4);
  int*      cursor     = (int*)A((size_t)NN * 4);
  int*      src_sorted = (int*)A((size_t)NE * 4);
  int*      gs         = (int*)A((size_t)(NG + 1) * 4);
  int*      counts     = (int*)A((size_t)NN * 4);

  const int nb16 = (NN + 15) / 16;     // 1250

  k_gemm_in<<<nb16, 256, 0, stream>>>(g_feats, W_in, b_in, h0, counts);
  k_hist<<<(NE + 255) / 256, 256, 0, stream>>>(dst, counts);
  k_scan_gbound<<<21, 1024, 0, stream>>>(counts, row_start, cursor, gid, gs);
  k_scatter<<<(NE + 255) / 256, 256, 0, stream>>>(dst, src, cursor, src_sorted);

  // layer 1
  k_gemm64pair<<<2 * nb16, 512, 0, stream>>>(h0, Wsrc1, bsrc1, Wdst1, bdst1, fsb, fd);
  k_gat_fused<<<NN, 512, 0, stream>>>(fsb, fd, src_sorted, row_start, attn1, bias1, h1, 1);

  // layer 2
  k_gemm64pair<<<2 * nb16, 512, 0, stream>>>(h1, Wsrc2, bsrc2, Wdst2, bdst2, fsb, fd);
  k_gat_fused<<<NN, 512, 0, stream>>>(fsb, fd, src_sorted, row_start, attn2, bias2, h2, 0);

  // readout + head
  k_head<<<NG, 256, 0, stream>>>(h2, gs, Wh1, bh1, Wh2, bh2, (float*)d_out);
}